// Round 3
// baseline (307.838 us; speedup 1.0000x reference)
//
#include <hip/hip_runtime.h>
#include <stdint.h>

#define PP 196            // 14*14
#define BP 6272           // 32*196

typedef _Float16 half_t;
typedef half_t half8v __attribute__((ext_vector_type(8)));
typedef half_t half4v __attribute__((ext_vector_type(4)));

// async global->LDS, 16 B per lane; LDS dest = wave-uniform base + lane*16
__device__ __forceinline__ void async_cp16(const void* g, void* l) {
  __builtin_amdgcn_global_load_lds(
      (const __attribute__((address_space(1))) void*)g,
      (__attribute__((address_space(3))) void*)l, 16, 0, 0);
}
__device__ __forceinline__ void wait_vm0() {
  // vmcnt(0), lgkmcnt/expcnt = no-wait
  __builtin_amdgcn_s_waitcnt(0x0f70);
}

// ---------------------------------------------------------------------------
// assign kernels: nearest-centroid 4-bit indices, packed 8 per u32, f64 math
// (must reproduce the np reference's argmin decisions exactly).
// dist = 0.5*c2 - dot  ==  0.5*(c2 - 2*dot): exact FP scaling, same ordering.
// idx layout: idxp[cb/8][BP]
// ---------------------------------------------------------------------------

template <typename T>
__global__ __launch_bounds__(256) void assign_1x1(
    const T* __restrict__ in, const float* __restrict__ cents,
    uint32_t* __restrict__ idxp, int nchan) {
  __shared__ double s_cent[8][16][4];
  __shared__ double s_c2[8][16];
  const int chunk = blockIdx.y;
  const int t = threadIdx.x;
  for (int i = t; i < 8 * 16 * 4; i += 256)
    ((double*)s_cent)[i] = (double)cents[(size_t)chunk * 512 + i];
  __syncthreads();
  if (t < 128) {
    int cb_l = t >> 4, k = t & 15;
    double s = 0.0;
#pragma unroll
    for (int d = 0; d < 4; d++) { double c = s_cent[cb_l][k][d]; s += c * c; }
    s_c2[cb_l][k] = 0.5 * s;
  }
  __syncthreads();
  const int p = blockIdx.x * 256 + t;
  if (p >= BP) return;
  const unsigned b = (unsigned)p / 196u;
  const unsigned pr = (unsigned)p - b * 196u;
  const T* xb = in + ((size_t)b * nchan + chunk * 32) * PP + pr;
  double xv[32];
#pragma unroll
  for (int i = 0; i < 32; i++) xv[i] = (double)xb[(size_t)i * PP];
  uint32_t word = 0;
#pragma unroll
  for (int cb_l = 0; cb_l < 8; cb_l++) {
    double best = 1e300; int bi = 0;
#pragma unroll
    for (int k = 0; k < 16; k++) {
      double dot = 0.0;
#pragma unroll
      for (int d = 0; d < 4; d++) dot = fma(xv[cb_l * 4 + d], s_cent[cb_l][k][d], dot);
      double dist = s_c2[cb_l][k] - dot;
      if (dist < best) { best = dist; bi = k; }   // strict <: first-min
    }
    word |= (uint32_t)bi << (4 * cb_l);
  }
  idxp[(size_t)chunk * BP + p] = word;
}

__global__ __launch_bounds__(256) void assign_3x3(
    const double* __restrict__ in, const float* __restrict__ cents,
    uint32_t* __restrict__ idxp) {
  __shared__ double s_cent[8][16][9];
  __shared__ double s_c2[8][16];
  const int chunk = blockIdx.y;
  const int c0 = chunk * 8;
  const int t = threadIdx.x;
  for (int i = t; i < 8 * 16 * 9; i += 256)
    ((double*)s_cent)[i] = (double)cents[(size_t)c0 * 144 + i];
  __syncthreads();
  if (t < 128) {
    int cb_l = t >> 4, k = t & 15;
    double s = 0.0;
#pragma unroll
    for (int d = 0; d < 9; d++) { double c = s_cent[cb_l][k][d]; s += c * c; }
    s_c2[cb_l][k] = 0.5 * s;
  }
  __syncthreads();
  const int p = blockIdx.x * 256 + t;
  if (p >= BP) return;
  const unsigned b = (unsigned)p / 196u;
  const unsigned pr = (unsigned)p - b * 196u;
  const int oh = pr / 14, ow = pr - oh * 14;
  uint32_t word = 0;
  for (int cb_l = 0; cb_l < 8; cb_l++) {
    const double* base = in + ((size_t)b * 256 + (c0 + cb_l)) * PP;
    double v[9];
#pragma unroll
    for (int i = 0; i < 3; i++) {
#pragma unroll
      for (int j = 0; j < 3; j++) {
        int hh = oh + i - 1, ww = ow + j - 1;
        bool ok = (hh >= 0) & (hh < 14) & (ww >= 0) & (ww < 14);
        v[i * 3 + j] = ok ? base[hh * 14 + ww] : 0.0;
      }
    }
    double best = 1e300; int bi = 0;
#pragma unroll
    for (int k = 0; k < 16; k++) {
      double dot = 0.0;
#pragma unroll
      for (int d = 0; d < 9; d++) dot = fma(v[d], s_cent[cb_l][k][d], dot);
      double dist = s_c2[cb_l][k] - dot;
      if (dist < best) { best = dist; bi = k; }
    }
    word |= (uint32_t)bi << (4 * cb_l);
  }
  idxp[(size_t)chunk * BP + p] = word;
}

// ---------------------------------------------------------------------------
// accum (f64): out[b][o][p] = act( scale[o]*sum_cb lut[cb][idx][o] + bias[o] (+res) )
// One barrier per chunk: async double-buffered global_load_lds staging.
// LDS chunk layout (per cb, 1 KB): slot(k,q) = k*4 + (q ^ ((k>>1)&3)), 16 B slots.
// Gather bank-quad = 4(idx&1) + (q^((idx>>1)&3)) -> distinct over idx mod 8,
// idx/idx+8 2-way alias (free). Staging is contiguous -> gl_lds-compatible.
// grid (49, NOUT/16), block 512: 128 positions x 16 out channels.
// ---------------------------------------------------------------------------
template <int NCB, int NOUT, bool RELU, bool RES, typename OutT>
__global__ __launch_bounds__(512) void accum_f64(
    const float* __restrict__ lut, const uint32_t* __restrict__ idxp,
    const float* __restrict__ scale, const float* __restrict__ bias,
    const float* __restrict__ res, OutT* __restrict__ out) {
  __shared__ float s_lut[2][4096];  // 2 x 16 KB
  const int t = threadIdx.x;
  const int lane = t & 63;
  const int wave = t >> 6;
  const int q = wave & 3;          // output quad (4 channels)
  const int pg = wave >> 2;        // 0..1
  const int p = blockIdx.x * 128 + pg * 64 + lane;
  const int o_base = blockIdx.y * 16;
  // staging source for this lane; wave stages cb_l = wave*2 + {0,1}
  const int sk = lane >> 2;
  const int sq = (lane & 3) ^ ((sk >> 1) & 3);
  const float* src0 = lut + ((size_t)(wave * 2) * 16 + sk) * NOUT + o_base + sq * 4;
  const float* src1 = src0 + (size_t)16 * NOUT;
  const size_t chunk_stride = (size_t)256 * NOUT;  // 16 cb * 16 k
  constexpr int NCHUNK = NCB / 16;

  async_cp16(src0, &s_lut[0][wave * 2 * 256]);
  async_cp16(src1, &s_lut[0][wave * 2 * 256 + 256]);
  uint32_t w0 = idxp[p];
  uint32_t w1 = idxp[(size_t)BP + p];
  double a0 = 0, a1 = 0, a2 = 0, a3 = 0;
  for (int ch = 0; ch < NCHUNK; ch++) {
    wait_vm0();
    __syncthreads();               // publishes chunk ch; ends ch-1 gathers
    uint32_t nw0 = 0, nw1 = 0;
    if (ch + 1 < NCHUNK) {
      const float* s0 = src0 + (size_t)(ch + 1) * chunk_stride;
      const float* s1 = src1 + (size_t)(ch + 1) * chunk_stride;
      float* d0 = &s_lut[(ch + 1) & 1][wave * 2 * 256];
      async_cp16(s0, d0);
      async_cp16(s1, d0 + 256);
      nw0 = idxp[(size_t)(2 * ch + 2) * BP + p];
      nw1 = idxp[(size_t)(2 * ch + 3) * BP + p];
    }
    const char* base = (const char*)&s_lut[ch & 1][0];
#pragma unroll
    for (int cb_l = 0; cb_l < 16; cb_l++) {
      uint32_t w = (cb_l < 8) ? w0 : w1;
      uint32_t idx = (w >> (4 * (cb_l & 7))) & 15u;
      uint32_t off = (idx << 6) + ((((uint32_t)q ^ (idx >> 1)) & 3u) << 4);
      const float4 v = *(const float4*)(base + cb_l * 1024 + off);
      a0 += (double)v.x; a1 += (double)v.y; a2 += (double)v.z; a3 += (double)v.w;
    }
    w0 = nw0; w1 = nw1;
  }
  const unsigned b = (unsigned)p / 196u;
  const unsigned pr = (unsigned)p - b * 196u;
  const int o = o_base + q * 4;
  const float4 sc = *(const float4*)(scale + o);
  const float4 bs = *(const float4*)(bias + o);
  double r0 = a0 * (double)sc.x + (double)bs.x;
  double r1 = a1 * (double)sc.y + (double)bs.y;
  double r2 = a2 * (double)sc.z + (double)bs.z;
  double r3 = a3 * (double)sc.w + (double)bs.w;
  if (RES) {
    const float* rp = res + ((size_t)b * NOUT + o) * PP + pr;
    r0 += (double)rp[0 * PP]; r1 += (double)rp[1 * PP];
    r2 += (double)rp[2 * PP]; r3 += (double)rp[3 * PP];
  }
  if (RELU) {
    r0 = fmax(r0, 0.0); r1 = fmax(r1, 0.0);
    r2 = fmax(r2, 0.0); r3 = fmax(r3, 0.0);
  }
  OutT* op = out + ((size_t)b * NOUT + o) * PP + pr;
  op[0 * PP] = (OutT)r0; op[1 * PP] = (OutT)r1;
  op[2 * PP] = (OutT)r2; op[3 * PP] = (OutT)r3;
}

// ---------------------------------------------------------------------------
// accum3 (f16 LUT, f32 accumulate): output-only precision (no downstream argmin).
// One b128 gather = 8 channels. LDS per cb = 512 B: slot(k,h) = k*2 + (h^((k>>2)&1)).
// Gather bank-quad = (2*idx + (h^((idx>>2)&1)))&7 -> distinct over idx mod 8,
// idx/idx+8 2-way (free). grid (49, 64), block 256: 128 positions x 16 ch.
// ---------------------------------------------------------------------------
__global__ __launch_bounds__(256) void accum3_f16(
    const half_t* __restrict__ lut16, const uint32_t* __restrict__ idxp,
    const float* __restrict__ scale, const float* __restrict__ bias,
    const float* __restrict__ res, float* __restrict__ out) {
  __shared__ half_t s_lut[2][4096];  // 2 x 8 KB
  const int t = threadIdx.x;
  const int lane = t & 63;
  const int wave = t >> 6;           // 0..3
  const int h = wave & 1;            // channel half (8 f16 ch)
  const int pg = wave >> 1;          // 0..1
  const int p = blockIdx.x * 128 + pg * 64 + lane;
  const int o_base = blockIdx.y * 16;
  // staging: instr j covers cb pair; lane -> cb (lane>>5), slot s5 = lane&31
  const int s5 = lane & 31;
  const int sk = s5 >> 1;
  const int sh = (s5 & 1) ^ ((sk >> 2) & 1);
  const int cbl0 = wave * 4 + (lane >> 5);       // j=0 cb; j=1 is +2
  const half_t* src0 = lut16 + ((size_t)cbl0 * 16 + sk) * 1024 + o_base + sh * 8;
  const half_t* src1 = src0 + (size_t)2 * 16 * 1024;
  const size_t chunk_stride = (size_t)16 * 16 * 1024;
  constexpr int NCHUNK = 4;

  async_cp16(src0, &s_lut[0][wave * 2 * 512]);
  async_cp16(src1, &s_lut[0][wave * 2 * 512 + 512]);
  uint32_t w0 = idxp[p];
  uint32_t w1 = idxp[(size_t)BP + p];
  float a[8];
#pragma unroll
  for (int i = 0; i < 8; i++) a[i] = 0.f;
  for (int ch = 0; ch < NCHUNK; ch++) {
    wait_vm0();
    __syncthreads();
    uint32_t nw0 = 0, nw1 = 0;
    if (ch + 1 < NCHUNK) {
      const half_t* s0 = src0 + (size_t)(ch + 1) * chunk_stride;
      const half_t* s1 = src1 + (size_t)(ch + 1) * chunk_stride;
      half_t* d0 = &s_lut[(ch + 1) & 1][wave * 2 * 512];
      async_cp16(s0, d0);
      async_cp16(s1, d0 + 512);
      nw0 = idxp[(size_t)(2 * ch + 2) * BP + p];
      nw1 = idxp[(size_t)(2 * ch + 3) * BP + p];
    }
    const char* base = (const char*)&s_lut[ch & 1][0];
#pragma unroll
    for (int cb_l = 0; cb_l < 16; cb_l++) {
      uint32_t w = (cb_l < 8) ? w0 : w1;
      uint32_t idx = (w >> (4 * (cb_l & 7))) & 15u;
      uint32_t off = (idx << 5) + ((((uint32_t)h ^ (idx >> 2)) & 1u) << 4);
      const half8v v = *(const half8v*)(base + cb_l * 512 + off);
#pragma unroll
      for (int i = 0; i < 8; i++) a[i] += (float)v[i];
    }
    w0 = nw0; w1 = nw1;
  }
  const unsigned b = (unsigned)p / 196u;
  const unsigned pr = (unsigned)p - b * 196u;
  const int o = o_base + h * 8;
  float r[8];
#pragma unroll
  for (int i = 0; i < 8; i++) r[i] = a[i] * scale[o + i] + bias[o + i];
  const float* rp = res + ((size_t)b * 1024 + o) * PP + pr;
  float* op = out + ((size_t)b * 1024 + o) * PP + pr;
#pragma unroll
  for (int i = 0; i < 8; i++) {
    float v = fmaxf(r[i] + rp[(size_t)i * PP], 0.f);
    op[(size_t)i * PP] = v;
  }
}

// f32 -> f16 LUT conversion (1,048,576 elements)
__global__ __launch_bounds__(256) void cvt_f16(
    const float* __restrict__ src, half_t* __restrict__ dst, int n) {
  int i = (blockIdx.x * 256 + threadIdx.x) * 4;
  if (i < n) {
    float4 v = *(const float4*)(src + i);
    half4v o;
    o[0] = (half_t)v.x; o[1] = (half_t)v.y; o[2] = (half_t)v.z; o[3] = (half_t)v.w;
    *(half4v*)(dst + i) = o;
  }
}

// ---------------------------------------------------------------------------

extern "C" void kernel_launch(void* const* d_in, const int* in_sizes, int n_in,
                              void* d_out, int out_size, void* d_ws, size_t ws_size,
                              hipStream_t stream) {
  const float* x   = (const float*)d_in[0];   // [32,1024,14,14]
  const float* c1c = (const float*)d_in[1];
  const float* c1l = (const float*)d_in[2];
  const float* c1s = (const float*)d_in[3];
  const float* c1b = (const float*)d_in[4];
  const float* c2c = (const float*)d_in[5];
  const float* c2l = (const float*)d_in[6];
  const float* c2s = (const float*)d_in[7];
  const float* c2b = (const float*)d_in[8];
  const float* c3c = (const float*)d_in[9];
  const float* c3l = (const float*)d_in[10];  // [64,16,1024]
  const float* c3s = (const float*)d_in[11];
  const float* c3b = (const float*)d_in[12];

  const size_t sz_i1 = (size_t)32 * BP * 4;
  const size_t sz_i2 = (size_t)32 * BP * 4;
  const size_t sz_i3 = (size_t)8 * BP * 4;
  const size_t sz_l16 = (size_t)64 * 16 * 1024 * 2;   // 2 MB
  const size_t sz_o64 = (size_t)BP * 256 * 8;          // 12.85 MB

  char* w = (char*)d_ws;
  uint32_t* i1 = (uint32_t*)w; w += sz_i1;
  uint32_t* i2 = (uint32_t*)w; w += sz_i2;
  uint32_t* i3 = (uint32_t*)w; w += sz_i3;
  const size_t base_need = sz_i1 + sz_i2 + sz_i3;
  bool use_f16 = (ws_size >= base_need + sz_l16);
  half_t* l16 = (half_t*)w;
  if (use_f16) w += sz_l16;
  double *out1, *out2;
  if (ws_size >= (size_t)(w - (char*)d_ws) + 2 * sz_o64) {
    out1 = (double*)w;
    out2 = (double*)(w + sz_o64);
  } else {
    // d_out (25.69 MB f32) == exactly two 12.85 MB f64 arrays; the final
    // accum3 reads only i3/x/lut, then overwrites all of d_out.
    out1 = (double*)d_out;
    out2 = out1 + (size_t)BP * 256;
  }

  const dim3 blkA(256);
  if (use_f16)
    cvt_f16<<<dim3(1024), blkA, 0, stream>>>(c3l, l16, 64 * 16 * 1024);
  // layer 1: 1x1, 256 codebooks (dsub=4) over 1024 input channels
  assign_1x1<float><<<dim3(25, 32), blkA, 0, stream>>>(x, c1c, i1, 1024);
  accum_f64<256, 256, true, false, double><<<dim3(49, 16), dim3(512), 0, stream>>>(
      c1l, i1, c1s, c1b, nullptr, out1);
  // layer 2: 3x3, 256 codebooks (dsub=9)
  assign_3x3<<<dim3(25, 32), blkA, 0, stream>>>(out1, c2c, i2);
  accum_f64<256, 256, true, false, double><<<dim3(49, 16), dim3(512), 0, stream>>>(
      c2l, i2, c2s, c2b, nullptr, out2);
  // layer 3: 1x1, 64 codebooks over 256 channels; fused residual + relu
  assign_1x1<double><<<dim3(25, 8), blkA, 0, stream>>>(out2, c3c, i3, 256);
  if (use_f16)
    accum3_f16<<<dim3(49, 64), blkA, 0, stream>>>(
        l16, i3, c3s, c3b, x, (float*)d_out);
  else
    accum_f64<64, 1024, true, true, float><<<dim3(49, 64), dim3(512), 0, stream>>>(
        c3l, i3, c3s, c3b, x, (float*)d_out);
}